// Round 6
// baseline (379.237 us; speedup 1.0000x reference)
//
#include <hip/hip_runtime.h>
#include <hip/hip_bf16.h>
#include <stdint.h>

typedef float  f32x4  __attribute__((ext_vector_type(4)));
typedef __bf16 bf16x8 __attribute__((ext_vector_type(8)));

#define DEV static __device__ __forceinline__

// XOR swizzle for LDS tiles with 128B rows: byte ^= ((row&7)<<4), row = byte>>7
DEV uint32_t swz128(uint32_t b){ return b ^ ((b>>3)&0x70u); }
// 256B rows: row = byte>>8
DEV uint32_t swz256(uint32_t b){ return b ^ ((b>>4)&0x70u); }

// async global->LDS, 16B per lane; LDS dest = wave-uniform base + lane*16
DEV void gl_lds16(const void* g, void* l) {
  __builtin_amdgcn_global_load_lds(
      (__attribute__((address_space(1))) void*)(g),
      (__attribute__((address_space(3))) void*)(l), 16, 0, 0);
}

DEV f32x4 mfma16(bf16x8 a, bf16x8 b, f32x4 c) {
  return __builtin_amdgcn_mfma_f32_16x16x32_bf16(a, b, c, 0, 0, 0);
}

// ---------------- depthwise 3x3 conv + BN (inference), fp32 in -> bf16 out ---
__global__ __launch_bounds__(256) void dwconv_bn_kernel(
    const float* __restrict__ x, const float* __restrict__ wdw,
    const float* __restrict__ gamma, const float* __restrict__ beta,
    const float* __restrict__ mean, const float* __restrict__ var,
    __hip_bfloat16* __restrict__ y, int Hout, int stride, int pad, int total)
{
  int idx = blockIdx.x*256 + threadIdx.x;
  if (idx >= total) return;
  int c = idx % 384;
  int t = idx / 384;
  int j = t % Hout; t /= Hout;
  int i = t % Hout; int b = t / Hout;
  float acc = 0.f;
  #pragma unroll
  for (int di=0; di<3; ++di) {
    int ii = i*stride + di - pad;
    if ((unsigned)ii < 56u) {
      #pragma unroll
      for (int dj=0; dj<3; ++dj) {
        int jj = j*stride + dj - pad;
        if ((unsigned)jj < 56u)
          acc += x[(size_t)(((b*56+ii)*56)+jj)*384 + c] * wdw[(di*3+dj)*384 + c];
      }
    }
  }
  float sc = gamma[c] * rsqrtf(var[c] + 1e-5f);
  y[idx] = __float2bfloat16((acc - mean[c]) * sc + beta[c]);
}

// ---------------- weight transpose: w(K,N) fp32 -> wT(N,K) bf16 --------------
__global__ __launch_bounds__(256) void transpose_w_kernel(
    const float* __restrict__ w, __hip_bfloat16* __restrict__ wT, int K, int N)
{
  int i = blockIdx.x*256 + threadIdx.x;
  if (i >= N*K) return;
  int n = i / K, k = i - n*K;
  wT[i] = __float2bfloat16(w[(size_t)k*N + n]);
}

// ---------------- 128x128x(K) bf16 GEMM, Bt = B^T (N,K) row-major ------------
// EPI 0: C=bf16 store. EPI 1: + scatter v-half transposed to vT[bh][d][p].
// EPI 2: bias + FP32 store to Cf (final output buffer is float).
template<int EPI>
__global__ __launch_bounds__(256,2) void gemm128_kernel(
    const __hip_bfloat16* __restrict__ A, const __hip_bfloat16* __restrict__ Bt,
    __hip_bfloat16* __restrict__ C, float* __restrict__ Cf, int M, int N, int K,
    const float* __restrict__ bias, __hip_bfloat16* __restrict__ vT)
{
  __shared__ __align__(1024) char As[128*64*2];
  __shared__ __align__(1024) char Bs[128*64*2];
  const int t = threadIdx.x;
  const int lane = t & 63;
  const int wave = t >> 6;
  const int wr = wave >> 1, wc = wave & 1;
  const int m0 = blockIdx.y*128, n0 = blockIdx.x*128;
  const int ldab = K*2;

  // pre-swizzled global sources: dest chunk d gets logical byte swz128(d)
  const char* aS[4]; const char* bS[4];
  #pragma unroll
  for (int j=0;j<4;++j) {
    uint32_t d = (uint32_t)(j*256 + t)*16u;
    uint32_t l = swz128(d);
    uint32_t r = l >> 7, cb = l & 127u;
    aS[j] = (const char*)A  + (size_t)(m0+(int)r)*ldab + cb;
    bS[j] = (const char*)Bt + (size_t)(n0+(int)r)*ldab + cb;
  }
  f32x4 acc[4][4];
  #pragma unroll
  for (int m=0;m<4;++m)
    #pragma unroll
    for (int n=0;n<4;++n)
      acc[m][n] = f32x4{0.f,0.f,0.f,0.f};

  const uint32_t kbOff = (uint32_t)((lane>>4)*16);
  const uint32_t arow = (uint32_t)(wr*64 + (lane&15));
  const uint32_t brow = (uint32_t)(wc*64 + (lane&15));

  const int nk = K >> 6;
  for (int kt=0; kt<nk; ++kt) {
    #pragma unroll
    for (int j=0;j<4;++j) {
      uint32_t d = (uint32_t)(j*256+t)*16u;
      gl_lds16(aS[j] + (size_t)kt*128, As + d);
      gl_lds16(bS[j] + (size_t)kt*128, Bs + d);
    }
    __syncthreads();
    #pragma unroll
    for (int ks=0;ks<2;++ks) {
      bf16x8 af[4], bf[4];
      #pragma unroll
      for (int m=0;m<4;++m)
        af[m] = *(const bf16x8*)(As + swz128((arow + m*16)*128 + ks*64 + kbOff));
      #pragma unroll
      for (int n=0;n<4;++n)
        bf[n] = *(const bf16x8*)(Bs + swz128((brow + n*16)*128 + ks*64 + kbOff));
      #pragma unroll
      for (int m=0;m<4;++m)
        #pragma unroll
        for (int n=0;n<4;++n)
          acc[m][n] = mfma16(af[m], bf[n], acc[m][n]);
    }
    __syncthreads();
  }
  #pragma unroll
  for (int m=0;m<4;++m) {
    #pragma unroll
    for (int n=0;n<4;++n) {
      #pragma unroll
      for (int i=0;i<4;++i) {
        int row = m0 + wr*64 + m*16 + (lane>>4)*4 + i;
        int col = n0 + wc*64 + n*16 + (lane&15);
        float v = acc[m][n][i];
        if (EPI==2) {
          Cf[(size_t)row*N + col] = v + bias[col];   // fp32 final output
        } else {
          C[(size_t)row*N + col] = __float2bfloat16(v);
          if (EPI==1 && col >= 384) {   // v-half: also write transposed per head
            int bb = row / 784;
            int p  = row - bb*784;
            int cc = col - 384;
            int hh = cc >> 6, dd = cc & 63;
            vT[(size_t)((bb*6+hh)*64+dd)*784 + p] = __float2bfloat16(v);
          }
        }
      }
    }
  }
}

// ---------------- flash attention: 64 q-rows/block, KVBLK=128, n_kv=784 ------
__global__ __launch_bounds__(256,2) void attn_kernel(
    const __hip_bfloat16* __restrict__ qb, const __hip_bfloat16* __restrict__ kvb,
    const __hip_bfloat16* __restrict__ vTb, __hip_bfloat16* __restrict__ ob)
{
  __shared__ __align__(1024) char Qs[64*128];     // 64 rows x 64 bf16 (swz128)
  __shared__ __align__(1024) char Ks[128*128];    // 128 kv rows x 64 d (swz128)
  __shared__ __align__(1024) char Vs[64*256];     // 64 d rows x 128 kv (swz256)
  __shared__ __align__(1024) char Ps[4][16*272];  // per-wave P, stride 272B (pad)
  const int t = threadIdx.x, lane = t&63, w = t>>6;
  const int bh = blockIdx.y;
  const int b = bh / 6, h = bh - b*6;
  const int qp0 = blockIdx.x * 64;

  // stage Q tile (rows strided in qbuf(25088,384), head offset h*64)
  const char* qbase = (const char*)qb + ((size_t)(b*3136 + qp0)*384 + h*64)*2;
  #pragma unroll
  for (int j=0;j<2;++j) {
    uint32_t d = (uint32_t)(j*256+t)*16u;
    uint32_t l = swz128(d);
    gl_lds16(qbase + (size_t)(l>>7)*768 + (l&127u), Qs + d);
  }
  __syncthreads();
  bf16x8 aq[2];
  #pragma unroll
  for (int ks=0;ks<2;++ks)
    aq[ks] = *(const bf16x8*)(Qs + swz128((uint32_t)(w*16 + (lane&15))*128 + ks*64 + (lane>>4)*16));

  float m_run[4], l_run[4];
  f32x4 o[4];
  #pragma unroll
  for (int i=0;i<4;++i){ m_run[i] = -1e30f; l_run[i] = 0.f; }
  #pragma unroll
  for (int nf=0;nf<4;++nf) o[nf] = f32x4{0.f,0.f,0.f,0.f};

  const char* kbase = (const char*)kvb + ((size_t)(b*784)*768 + h*64)*2;
  const char* vbase = (const char*)vTb + (size_t)((b*6+h)*64)*1568;

  for (int kt=0; kt<7; ++kt) {
    const int kv0 = kt*128;
    #pragma unroll
    for (int j=0;j<4;++j) {               // K tile, kv rows clamped (masked later)
      uint32_t d = (uint32_t)(j*256+t)*16u;
      uint32_t l = swz128(d);
      int kvr = kv0 + (int)(l>>7); if (kvr > 783) kvr = 783;
      gl_lds16(kbase + (size_t)kvr*1536 + (l&127u), Ks + d);
    }
    #pragma unroll
    for (int j=0;j<4;++j) {               // V^T tile (overrun lands in ws slack)
      uint32_t d = (uint32_t)(j*256+t)*16u;
      uint32_t l = swz256(d);
      gl_lds16(vbase + (size_t)(l>>8)*1568 + (size_t)kv0*2 + (l&255u), Vs + d);
    }
    __syncthreads();

    // S = Q K^T
    f32x4 s[8];
    #pragma unroll
    for (int nf=0;nf<8;++nf) s[nf] = f32x4{0.f,0.f,0.f,0.f};
    #pragma unroll
    for (int nf=0;nf<8;++nf) {
      #pragma unroll
      for (int ks=0;ks<2;++ks) {
        bf16x8 kf = *(const bf16x8*)(Ks + swz128((uint32_t)(nf*16+(lane&15))*128 + ks*64 + (lane>>4)*16));
        s[nf] = mfma16(aq[ks], kf, s[nf]);
      }
    }

    // scale + tail mask + online softmax (rows = (lane>>4)*4+i, cols across 16 lanes)
    float pmax[4];
    #pragma unroll
    for (int i=0;i<4;++i) pmax[i] = -1e30f;
    const int colb = kv0 + (lane&15);
    #pragma unroll
    for (int nf=0;nf<8;++nf) {
      #pragma unroll
      for (int i=0;i<4;++i) {
        float v = s[nf][i]*0.125f;
        if (colb + nf*16 >= 784) v = -1e30f;
        s[nf][i] = v;
        pmax[i] = fmaxf(pmax[i], v);
      }
    }
    #pragma unroll
    for (int i=0;i<4;++i) {
      #pragma unroll
      for (int off=8; off>=1; off>>=1)
        pmax[i] = fmaxf(pmax[i], __shfl_xor(pmax[i], off));
    }
    float f[4], mn[4], ps[4];
    #pragma unroll
    for (int i=0;i<4;++i) {
      mn[i] = fmaxf(m_run[i], pmax[i]);
      f[i] = __expf(m_run[i] - mn[i]);
      m_run[i] = mn[i];
      l_run[i] *= f[i];
      ps[i] = 0.f;
    }
    #pragma unroll
    for (int nf=0;nf<4;++nf)
      #pragma unroll
      for (int i=0;i<4;++i)
        o[nf][i] *= f[i];
    char* pw = Ps[w] + ((lane>>4)*4)*272 + (lane&15)*2;
    #pragma unroll
    for (int nf=0;nf<8;++nf) {
      #pragma unroll
      for (int i=0;i<4;++i) {
        float p = __expf(s[nf][i] - mn[i]);
        ps[i] += p;
        *(__hip_bfloat16*)(pw + i*272 + nf*32) = __float2bfloat16(p);
      }
    }
    #pragma unroll
    for (int i=0;i<4;++i) {
      #pragma unroll
      for (int off=8; off>=1; off>>=1)
        ps[i] += __shfl_xor(ps[i], off);
      l_run[i] += ps[i];
    }
    __syncthreads();   // P visible + ordered; Vs still valid
    // O += P V
    #pragma unroll
    for (int ks=0;ks<4;++ks) {
      bf16x8 pa = *(const bf16x8*)(Ps[w] + (lane&15)*272 + ks*64 + (lane>>4)*16);
      #pragma unroll
      for (int nf=0;nf<4;++nf) {
        bf16x8 vf = *(const bf16x8*)(Vs + swz256((uint32_t)(nf*16+(lane&15))*256 + ks*64 + (lane>>4)*16));
        o[nf] = mfma16(pa, vf, o[nf]);
      }
    }
    __syncthreads();   // all waves done reading Ks/Vs before next stage
  }
  char* obase = (char*)ob + ((size_t)(b*3136 + qp0 + w*16 + (lane>>4)*4)*384 + h*64 + (lane&15))*2;
  #pragma unroll
  for (int i=0;i<4;++i) {
    float inv = 1.0f / l_run[i];
    #pragma unroll
    for (int nf=0;nf<4;++nf)
      *(__hip_bfloat16*)(obase + (size_t)i*768 + nf*32) = __float2bfloat16(o[nf][i]*inv);
  }
}

// ---------------- launch --------------------------------------------------
extern "C" void kernel_launch(void* const* d_in, const int* in_sizes, int n_in,
                              void* d_out, int out_size, void* d_ws, size_t ws_size,
                              hipStream_t stream)
{
  const float* x      = (const float*)d_in[0];
  const float* wdwq   = (const float*)d_in[1];
  const float* gq     = (const float*)d_in[2];
  const float* bq     = (const float*)d_in[3];
  const float* mq     = (const float*)d_in[4];
  const float* vq     = (const float*)d_in[5];
  const float* wpwq   = (const float*)d_in[6];
  const float* wdwkv  = (const float*)d_in[7];
  const float* gkv    = (const float*)d_in[8];
  const float* bkv    = (const float*)d_in[9];
  const float* mkv    = (const float*)d_in[10];
  const float* vkv    = (const float*)d_in[11];
  const float* wpwkv  = (const float*)d_in[12];
  const float* wout   = (const float*)d_in[13];
  const float* bout   = (const float*)d_in[14];

  char* ws = (char*)d_ws;
  // offsets (bytes); o_buf aliases y_q (dead after q GEMM)
  __hip_bfloat16* yq    = (__hip_bfloat16*)(ws + 0);          // 25088x384
  __hip_bfloat16* qbuf  = (__hip_bfloat16*)(ws + 19267584);   // 25088x384
  __hip_bfloat16* ykv   = (__hip_bfloat16*)(ws + 38535168);   // 6272x384
  __hip_bfloat16* kvbuf = (__hip_bfloat16*)(ws + 43352064);   // 6272x768
  __hip_bfloat16* vT    = (__hip_bfloat16*)(ws + 52985856);   // 48x64x784 (+64K slack)
  __hip_bfloat16* wTq   = (__hip_bfloat16*)(ws + 57868288);   // 384x384
  __hip_bfloat16* wTkv  = (__hip_bfloat16*)(ws + 58163200);   // 768x384
  __hip_bfloat16* wTo   = (__hip_bfloat16*)(ws + 58753024);   // 384x384

  dwconv_bn_kernel<<<dim3(37632),256,0,stream>>>(x,wdwq,gq,bq,mq,vq,yq,56,1,1,9633792);
  dwconv_bn_kernel<<<dim3(9408),256,0,stream>>>(x,wdwkv,gkv,bkv,mkv,vkv,ykv,28,2,0,2408448);
  transpose_w_kernel<<<dim3(576),256,0,stream>>>(wpwq, wTq, 384, 384);
  transpose_w_kernel<<<dim3(1152),256,0,stream>>>(wpwkv, wTkv, 384, 768);
  transpose_w_kernel<<<dim3(576),256,0,stream>>>(wout, wTo, 384, 384);
  gemm128_kernel<0><<<dim3(3,196),256,0,stream>>>(yq, wTq, qbuf, nullptr, 25088,384,384, nullptr, nullptr);
  gemm128_kernel<1><<<dim3(6,49),256,0,stream>>>(ykv, wTkv, kvbuf, nullptr, 6272,768,384, nullptr, vT);
  attn_kernel<<<dim3(49,48),256,0,stream>>>(qbuf, kvbuf, vT, yq);
  gemm128_kernel<2><<<dim3(3,196),256,0,stream>>>(yq, wTo, nullptr, (float*)d_out, 25088,384,384, bout, nullptr);
}

// Round 7
// 363.138 us; speedup vs baseline: 1.0443x; 1.0443x over previous
//
#include <hip/hip_runtime.h>
#include <hip/hip_bf16.h>
#include <stdint.h>

typedef float  f32x4  __attribute__((ext_vector_type(4)));
typedef __bf16 bf16x8 __attribute__((ext_vector_type(8)));

#define DEV static __device__ __forceinline__

// XOR swizzle for LDS tiles with 128B rows: byte ^= ((row&7)<<4), row = byte>>7
DEV uint32_t swz128(uint32_t b){ return b ^ ((b>>3)&0x70u); }

// async global->LDS, 16B per lane; LDS dest = wave-uniform base + lane*16
DEV void gl_lds16(const void* g, void* l) {
  __builtin_amdgcn_global_load_lds(
      (__attribute__((address_space(1))) void*)(g),
      (__attribute__((address_space(3))) void*)(l), 16, 0, 0);
}

DEV f32x4 mfma16(bf16x8 a, bf16x8 b, f32x4 c) {
  return __builtin_amdgcn_mfma_f32_16x16x32_bf16(a, b, c, 0, 0, 0);
}

// ---------------- depthwise 3x3 conv + BN (inference), fp32 in -> bf16 out ---
__global__ __launch_bounds__(256) void dwconv_bn_kernel(
    const float* __restrict__ x, const float* __restrict__ wdw,
    const float* __restrict__ gamma, const float* __restrict__ beta,
    const float* __restrict__ mean, const float* __restrict__ var,
    __hip_bfloat16* __restrict__ y, int Hout, int stride, int pad, int total)
{
  int idx = blockIdx.x*256 + threadIdx.x;
  if (idx >= total) return;
  int c = idx % 384;
  int t = idx / 384;
  int j = t % Hout; t /= Hout;
  int i = t % Hout; int b = t / Hout;
  float acc = 0.f;
  #pragma unroll
  for (int di=0; di<3; ++di) {
    int ii = i*stride + di - pad;
    if ((unsigned)ii < 56u) {
      #pragma unroll
      for (int dj=0; dj<3; ++dj) {
        int jj = j*stride + dj - pad;
        if ((unsigned)jj < 56u)
          acc += x[(size_t)(((b*56+ii)*56)+jj)*384 + c] * wdw[(di*3+dj)*384 + c];
      }
    }
  }
  float sc = gamma[c] * rsqrtf(var[c] + 1e-5f);
  y[idx] = __float2bfloat16((acc - mean[c]) * sc + beta[c]);
}

// ---------------- merged weight transposes: w(K,N) fp32 -> wT(N,K) bf16 ------
__global__ __launch_bounds__(256) void transpose_all_kernel(
    const float* __restrict__ wq, const float* __restrict__ wkv,
    const float* __restrict__ wo,
    __hip_bfloat16* __restrict__ wTq, __hip_bfloat16* __restrict__ wTkv,
    __hip_bfloat16* __restrict__ wTo)
{
  int i = blockIdx.x*256 + threadIdx.x;
  if (i < 147456) {                       // 384x384
    int n = i / 384, k = i - n*384;
    wTq[i] = __float2bfloat16(wq[(size_t)k*384 + n]);
  } else if (i < 147456 + 294912) {       // 768x384 (N=768)
    int idx = i - 147456;
    int n = idx / 384, k = idx - n*384;
    wTkv[idx] = __float2bfloat16(wkv[(size_t)k*768 + n]);
  } else if (i < 147456 + 294912 + 147456) {
    int idx = i - 442368;
    int n = idx / 384, k = idx - n*384;
    wTo[idx] = __float2bfloat16(wo[(size_t)k*384 + n]);
  }
}

// ---------------- 128x128x(K) bf16 GEMM, Bt = B^T (N,K) row-major ------------
// EPI 0: C=bf16 store. EPI 1: + scatter v-half transposed to vT[bh][d][p].
// EPI 2: bias + FP32 store to Cf (final output buffer is float).
template<int EPI>
__global__ __launch_bounds__(256,2) void gemm128_kernel(
    const __hip_bfloat16* __restrict__ A, const __hip_bfloat16* __restrict__ Bt,
    __hip_bfloat16* __restrict__ C, float* __restrict__ Cf, int M, int N, int K,
    const float* __restrict__ bias, __hip_bfloat16* __restrict__ vT)
{
  __shared__ __align__(1024) char As[128*64*2];
  __shared__ __align__(1024) char Bs[128*64*2];
  const int t = threadIdx.x;
  const int lane = t & 63;
  const int wave = t >> 6;
  const int wr = wave >> 1, wc = wave & 1;
  const int m0 = blockIdx.y*128, n0 = blockIdx.x*128;
  const int ldab = K*2;

  const char* aS[4]; const char* bS[4];
  #pragma unroll
  for (int j=0;j<4;++j) {
    uint32_t d = (uint32_t)(j*256 + t)*16u;
    uint32_t l = swz128(d);
    uint32_t r = l >> 7, cb = l & 127u;
    aS[j] = (const char*)A  + (size_t)(m0+(int)r)*ldab + cb;
    bS[j] = (const char*)Bt + (size_t)(n0+(int)r)*ldab + cb;
  }
  f32x4 acc[4][4];
  #pragma unroll
  for (int m=0;m<4;++m)
    #pragma unroll
    for (int n=0;n<4;++n)
      acc[m][n] = f32x4{0.f,0.f,0.f,0.f};

  const uint32_t kbOff = (uint32_t)((lane>>4)*16);
  const uint32_t arow = (uint32_t)(wr*64 + (lane&15));
  const uint32_t brow = (uint32_t)(wc*64 + (lane&15));

  const int nk = K >> 6;
  for (int kt=0; kt<nk; ++kt) {
    #pragma unroll
    for (int j=0;j<4;++j) {
      uint32_t d = (uint32_t)(j*256+t)*16u;
      gl_lds16(aS[j] + (size_t)kt*128, As + d);
      gl_lds16(bS[j] + (size_t)kt*128, Bs + d);
    }
    __syncthreads();
    #pragma unroll
    for (int ks=0;ks<2;++ks) {
      bf16x8 af[4], bf[4];
      #pragma unroll
      for (int m=0;m<4;++m)
        af[m] = *(const bf16x8*)(As + swz128((arow + m*16)*128 + ks*64 + kbOff));
      #pragma unroll
      for (int n=0;n<4;++n)
        bf[n] = *(const bf16x8*)(Bs + swz128((brow + n*16)*128 + ks*64 + kbOff));
      #pragma unroll
      for (int m=0;m<4;++m)
        #pragma unroll
        for (int n=0;n<4;++n)
          acc[m][n] = mfma16(af[m], bf[n], acc[m][n]);
    }
    __syncthreads();
  }
  #pragma unroll
  for (int m=0;m<4;++m) {
    #pragma unroll
    for (int n=0;n<4;++n) {
      #pragma unroll
      for (int i=0;i<4;++i) {
        int row = m0 + wr*64 + m*16 + (lane>>4)*4 + i;
        int col = n0 + wc*64 + n*16 + (lane&15);
        float v = acc[m][n][i];
        if (EPI==2) {
          Cf[(size_t)row*N + col] = v + bias[col];   // fp32 final output
        } else {
          C[(size_t)row*N + col] = __float2bfloat16(v);
          if (EPI==1 && col >= 384) {   // v-half: also write transposed per head
            int bb = row / 784;
            int p  = row - bb*784;
            int cc = col - 384;
            int hh = cc >> 6, dd = cc & 63;
            vT[(size_t)((bb*6+hh)*64+dd)*784 + p] = __float2bfloat16(v);
          }
        }
      }
    }
  }
}

// ---------------- flash attention v2: 64 q-rows/block, KVBLK=64, dbuf --------
// LDS = K 2x8K + V 2x8K + P 4x2K = 40960 B -> 4 blocks/CU. Q in registers.
// One barrier per kv-tile; staging for tile t+1 issued at top of tile t.
__global__ __launch_bounds__(256,4) void attn_kernel(
    const __hip_bfloat16* __restrict__ qb, const __hip_bfloat16* __restrict__ kvb,
    const __hip_bfloat16* __restrict__ vTb, __hip_bfloat16* __restrict__ ob)
{
  __shared__ __align__(1024) char Ks[2*8192];   // [buf][64 kv x 64 d] swz128
  __shared__ __align__(1024) char Vs[2*8192];   // [buf][64 d x 64 kv] swz128
  __shared__ __align__(1024) char Ps[4*2048];   // per-wave [16 q x 64 kv] swz128
  const int t = threadIdx.x, lane = t&63, w = t>>6;
  const int bh = blockIdx.y;
  const int b = bh / 6, h = bh - b*6;
  const int qp0 = blockIdx.x * 64;

  // Q fragments direct from global (A-frag: row=lane&15, k-blk=lane>>4)
  const char* qrow = (const char*)qb
      + ((size_t)(b*3136 + qp0 + w*16 + (lane&15))*384 + h*64)*2 + (lane>>4)*16;
  bf16x8 aq[2];
  aq[0] = *(const bf16x8*)(qrow);
  aq[1] = *(const bf16x8*)(qrow + 64);

  const char* kbase = (const char*)kvb + ((size_t)(b*784)*768 + h*64)*2;  // row 1536B
  const char* vbase = (const char*)vTb + (size_t)((b*6+h)*64)*1568;       // row 1568B

  // precomputed staging geometry (per thread, loop-invariant)
  const uint32_t d0 = (uint32_t)t*16u, d1 = (uint32_t)(256+t)*16u;
  const uint32_t l0 = swz128(d0), l1 = swz128(d1);
  const int      kr0 = (int)(l0>>7), kr1 = (int)(l1>>7);   // tile row 0..63
  const uint32_t c0 = l0&127u, c1 = l1&127u;

  #define STAGE(buf, kv0) do {                                               \
    int a0 = (kv0)+kr0; if (a0>783) a0=783;                                  \
    int a1 = (kv0)+kr1; if (a1>783) a1=783;                                  \
    gl_lds16(kbase + (size_t)a0*1536 + c0, Ks + (buf)*8192 + d0);            \
    gl_lds16(kbase + (size_t)a1*1536 + c1, Ks + (buf)*8192 + d1);            \
    gl_lds16(vbase + (size_t)kr0*1568 + (size_t)(kv0)*2 + c0, Vs + (buf)*8192 + d0); \
    gl_lds16(vbase + (size_t)kr1*1568 + (size_t)(kv0)*2 + c1, Vs + (buf)*8192 + d1); \
  } while(0)

  STAGE(0, 0);
  asm volatile("s_waitcnt vmcnt(0)" ::: "memory");
  __syncthreads();

  float m_run[4], l_run[4];
  f32x4 o[4];
  #pragma unroll
  for (int i=0;i<4;++i){ m_run[i] = -1e30f; l_run[i] = 0.f; }
  #pragma unroll
  for (int nf=0;nf<4;++nf) o[nf] = f32x4{0.f,0.f,0.f,0.f};

  char* Pb = Ps + w*2048;
  const uint32_t fragOff = (uint32_t)((lane>>4)*16);

  for (int kt=0; kt<13; ++kt) {
    const int cur = kt & 1;
    STAGE(cur^1, (kt+1)*64);          // prefetch next tile (whole iter to land)
    const char* Kb = Ks + cur*8192;
    const char* Vb = Vs + cur*8192;

    // S = Q K^T (4 col-frags x 2 k-slices)
    f32x4 s[4];
    #pragma unroll
    for (int nf=0;nf<4;++nf) s[nf] = f32x4{0.f,0.f,0.f,0.f};
    #pragma unroll
    for (int nf=0;nf<4;++nf) {
      #pragma unroll
      for (int ks=0;ks<2;++ks) {
        bf16x8 kf = *(const bf16x8*)(Kb + swz128((uint32_t)(nf*16+(lane&15))*128 + ks*64 + fragOff));
        s[nf] = mfma16(aq[ks], kf, s[nf]);
      }
    }

    // scale + tail mask + online softmax
    float pmax[4];
    #pragma unroll
    for (int i=0;i<4;++i) pmax[i] = -1e30f;
    const int colb = kt*64 + (lane&15);
    #pragma unroll
    for (int nf=0;nf<4;++nf) {
      #pragma unroll
      for (int i=0;i<4;++i) {
        float v = s[nf][i]*0.125f;
        if (colb + nf*16 >= 784) v = -1e30f;
        s[nf][i] = v;
        pmax[i] = fmaxf(pmax[i], v);
      }
    }
    #pragma unroll
    for (int i=0;i<4;++i) {
      #pragma unroll
      for (int off=8; off>=1; off>>=1)
        pmax[i] = fmaxf(pmax[i], __shfl_xor(pmax[i], off));
    }
    float f[4], mn[4], ps[4];
    #pragma unroll
    for (int i=0;i<4;++i) {
      mn[i] = fmaxf(m_run[i], pmax[i]);
      f[i] = __expf(m_run[i] - mn[i]);
      m_run[i] = mn[i];
      l_run[i] *= f[i];
      ps[i] = 0.f;
    }
    #pragma unroll
    for (int nf=0;nf<4;++nf)
      #pragma unroll
      for (int i=0;i<4;++i)
        o[nf][i] *= f[i];
    #pragma unroll
    for (int nf=0;nf<4;++nf) {
      #pragma unroll
      for (int i=0;i<4;++i) {
        float p = __expf(s[nf][i] - mn[i]);
        ps[i] += p;
        uint32_t off = (uint32_t)((lane>>4)*4+i)*128 + (uint32_t)(nf*16+(lane&15))*2;
        *(__hip_bfloat16*)(Pb + swz128(off)) = __float2bfloat16(p);
      }
    }
    #pragma unroll
    for (int i=0;i<4;++i) {
      #pragma unroll
      for (int off=8; off>=1; off>>=1)
        ps[i] += __shfl_xor(ps[i], off);
      l_run[i] += ps[i];
    }

    // O += P V  (P per-wave private; compiler orders ds_write->ds_read)
    #pragma unroll
    for (int ks=0;ks<2;++ks) {
      bf16x8 pa = *(const bf16x8*)(Pb + swz128((uint32_t)(lane&15)*128 + ks*64 + fragOff));
      #pragma unroll
      for (int nf=0;nf<4;++nf) {
        bf16x8 vf = *(const bf16x8*)(Vb + swz128((uint32_t)(nf*16+(lane&15))*128 + ks*64 + fragOff));
        o[nf] = mfma16(pa, vf, o[nf]);
      }
    }

    asm volatile("s_waitcnt vmcnt(0)" ::: "memory");  // next tile staged
    __syncthreads();                                   // + all waves done w/ cur
  }
  #undef STAGE

  char* obase = (char*)ob + ((size_t)(b*3136 + qp0 + w*16 + (lane>>4)*4)*384 + h*64 + (lane&15))*2;
  #pragma unroll
  for (int i=0;i<4;++i) {
    float inv = 1.0f / l_run[i];
    #pragma unroll
    for (int nf=0;nf<4;++nf)
      *(__hip_bfloat16*)(obase + (size_t)i*768 + nf*32) = __float2bfloat16(o[nf][i]*inv);
  }
}

// ---------------- launch --------------------------------------------------
extern "C" void kernel_launch(void* const* d_in, const int* in_sizes, int n_in,
                              void* d_out, int out_size, void* d_ws, size_t ws_size,
                              hipStream_t stream)
{
  const float* x      = (const float*)d_in[0];
  const float* wdwq   = (const float*)d_in[1];
  const float* gq     = (const float*)d_in[2];
  const float* bq     = (const float*)d_in[3];
  const float* mq     = (const float*)d_in[4];
  const float* vq     = (const float*)d_in[5];
  const float* wpwq   = (const float*)d_in[6];
  const float* wdwkv  = (const float*)d_in[7];
  const float* gkv    = (const float*)d_in[8];
  const float* bkv    = (const float*)d_in[9];
  const float* mkv    = (const float*)d_in[10];
  const float* vkv    = (const float*)d_in[11];
  const float* wpwkv  = (const float*)d_in[12];
  const float* wout   = (const float*)d_in[13];
  const float* bout   = (const float*)d_in[14];

  char* ws = (char*)d_ws;
  __hip_bfloat16* yq    = (__hip_bfloat16*)(ws + 0);          // 25088x384 (reused as o)
  __hip_bfloat16* qbuf  = (__hip_bfloat16*)(ws + 19267584);   // 25088x384
  __hip_bfloat16* ykv   = (__hip_bfloat16*)(ws + 38535168);   // 6272x384
  __hip_bfloat16* kvbuf = (__hip_bfloat16*)(ws + 43352064);   // 6272x768
  __hip_bfloat16* vT    = (__hip_bfloat16*)(ws + 52985856);   // 48x64x784 (+64K slack)
  __hip_bfloat16* wTq   = (__hip_bfloat16*)(ws + 57868288);   // 384x384
  __hip_bfloat16* wTkv  = (__hip_bfloat16*)(ws + 58163200);   // 768x384
  __hip_bfloat16* wTo   = (__hip_bfloat16*)(ws + 58753024);   // 384x384

  dwconv_bn_kernel<<<dim3(37632),256,0,stream>>>(x,wdwq,gq,bq,mq,vq,yq,56,1,1,9633792);
  dwconv_bn_kernel<<<dim3(9408),256,0,stream>>>(x,wdwkv,gkv,bkv,mkv,vkv,ykv,28,2,0,2408448);
  transpose_all_kernel<<<dim3(2304),256,0,stream>>>(wpwq, wpwkv, wout, wTq, wTkv, wTo);
  gemm128_kernel<0><<<dim3(3,196),256,0,stream>>>(yq, wTq, qbuf, nullptr, 25088,384,384, nullptr, nullptr);
  gemm128_kernel<1><<<dim3(6,49),256,0,stream>>>(ykv, wTkv, kvbuf, nullptr, 6272,768,384, nullptr, vT);
  attn_kernel<<<dim3(49,48),256,0,stream>>>(qbuf, kvbuf, vT, yq);
  gemm128_kernel<2><<<dim3(3,196),256,0,stream>>>(yq, wTo, nullptr, (float*)d_out, 25088,384,384, bout, nullptr);
}

// Round 8
// 333.728 us; speedup vs baseline: 1.1364x; 1.0881x over previous
//
#include <hip/hip_runtime.h>
#include <hip/hip_bf16.h>
#include <stdint.h>

typedef float  f32x4  __attribute__((ext_vector_type(4)));
typedef __bf16 bf16x8 __attribute__((ext_vector_type(8)));

#define DEV static __device__ __forceinline__

// XOR swizzle for LDS tiles with 128B rows: byte ^= ((row&7)<<4), row = byte>>7
DEV uint32_t swz128(uint32_t b){ return b ^ ((b>>3)&0x70u); }

// async global->LDS, 16B per lane; LDS dest = wave-uniform base + lane*16
DEV void gl_lds16(const void* g, void* l) {
  __builtin_amdgcn_global_load_lds(
      (__attribute__((address_space(1))) void*)(g),
      (__attribute__((address_space(3))) void*)(l), 16, 0, 0);
}

DEV f32x4 mfma16(bf16x8 a, bf16x8 b, f32x4 c) {
  return __builtin_amdgcn_mfma_f32_16x16x32_bf16(a, b, c, 0, 0, 0);
}

DEV uint32_t pkbf(float a, float b) {
  union { __hip_bfloat162 v; uint32_t u; } c;
  c.v.x = __float2bfloat16(a);
  c.v.y = __float2bfloat16(b);
  return c.u;
}

// ---------------- depthwise 3x3 conv + BN (inference), fp32 in -> bf16 out ---
__global__ __launch_bounds__(256) void dwconv_bn_kernel(
    const float* __restrict__ x, const float* __restrict__ wdw,
    const float* __restrict__ gamma, const float* __restrict__ beta,
    const float* __restrict__ mean, const float* __restrict__ var,
    __hip_bfloat16* __restrict__ y, int Hout, int stride, int pad, int total)
{
  int idx = blockIdx.x*256 + threadIdx.x;
  if (idx >= total) return;
  int c = idx % 384;
  int t = idx / 384;
  int j = t % Hout; t /= Hout;
  int i = t % Hout; int b = t / Hout;
  float acc = 0.f;
  #pragma unroll
  for (int di=0; di<3; ++di) {
    int ii = i*stride + di - pad;
    if ((unsigned)ii < 56u) {
      #pragma unroll
      for (int dj=0; dj<3; ++dj) {
        int jj = j*stride + dj - pad;
        if ((unsigned)jj < 56u)
          acc += x[(size_t)(((b*56+ii)*56)+jj)*384 + c] * wdw[(di*3+dj)*384 + c];
      }
    }
  }
  float sc = gamma[c] * rsqrtf(var[c] + 1e-5f);
  y[idx] = __float2bfloat16((acc - mean[c]) * sc + beta[c]);
}

// ---------------- merged weight transposes: w(K,N) fp32 -> wT(N,K) bf16 ------
__global__ __launch_bounds__(256) void transpose_all_kernel(
    const float* __restrict__ wq, const float* __restrict__ wkv,
    const float* __restrict__ wo,
    __hip_bfloat16* __restrict__ wTq, __hip_bfloat16* __restrict__ wTkv,
    __hip_bfloat16* __restrict__ wTo)
{
  int i = blockIdx.x*256 + threadIdx.x;
  if (i < 147456) {                       // 384x384
    int n = i / 384, k = i - n*384;
    wTq[i] = __float2bfloat16(wq[(size_t)k*384 + n]);
  } else if (i < 147456 + 294912) {       // 768x384 (N=768)
    int idx = i - 147456;
    int n = idx / 384, k = idx - n*384;
    wTkv[idx] = __float2bfloat16(wkv[(size_t)k*768 + n]);
  } else if (i < 147456 + 294912 + 147456) {
    int idx = i - 442368;
    int n = idx / 384, k = idx - n*384;
    wTo[idx] = __float2bfloat16(wo[(size_t)k*384 + n]);
  }
}

// ---------------- 128x128x(K) bf16 GEMM, Bt = B^T (N,K) row-major ------------
// EPI 0: C=bf16 store. EPI 1: + scatter v-half transposed to vT[bh][d][p].
// EPI 2: bias + FP32 store to Cf (final output buffer is float).
template<int EPI>
__global__ __launch_bounds__(256,2) void gemm128_kernel(
    const __hip_bfloat16* __restrict__ A, const __hip_bfloat16* __restrict__ Bt,
    __hip_bfloat16* __restrict__ C, float* __restrict__ Cf, int M, int N, int K,
    const float* __restrict__ bias, __hip_bfloat16* __restrict__ vT)
{
  __shared__ __align__(1024) char As[128*64*2];
  __shared__ __align__(1024) char Bs[128*64*2];
  const int t = threadIdx.x;
  const int lane = t & 63;
  const int wave = t >> 6;
  const int wr = wave >> 1, wc = wave & 1;
  const int m0 = blockIdx.y*128, n0 = blockIdx.x*128;
  const int ldab = K*2;

  const char* aS[4]; const char* bS[4];
  #pragma unroll
  for (int j=0;j<4;++j) {
    uint32_t d = (uint32_t)(j*256 + t)*16u;
    uint32_t l = swz128(d);
    uint32_t r = l >> 7, cb = l & 127u;
    aS[j] = (const char*)A  + (size_t)(m0+(int)r)*ldab + cb;
    bS[j] = (const char*)Bt + (size_t)(n0+(int)r)*ldab + cb;
  }
  f32x4 acc[4][4];
  #pragma unroll
  for (int m=0;m<4;++m)
    #pragma unroll
    for (int n=0;n<4;++n)
      acc[m][n] = f32x4{0.f,0.f,0.f,0.f};

  const uint32_t kbOff = (uint32_t)((lane>>4)*16);
  const uint32_t arow = (uint32_t)(wr*64 + (lane&15));
  const uint32_t brow = (uint32_t)(wc*64 + (lane&15));

  const int nk = K >> 6;
  for (int kt=0; kt<nk; ++kt) {
    #pragma unroll
    for (int j=0;j<4;++j) {
      uint32_t d = (uint32_t)(j*256+t)*16u;
      gl_lds16(aS[j] + (size_t)kt*128, As + d);
      gl_lds16(bS[j] + (size_t)kt*128, Bs + d);
    }
    __syncthreads();
    #pragma unroll
    for (int ks=0;ks<2;++ks) {
      bf16x8 af[4], bf[4];
      #pragma unroll
      for (int m=0;m<4;++m)
        af[m] = *(const bf16x8*)(As + swz128((arow + m*16)*128 + ks*64 + kbOff));
      #pragma unroll
      for (int n=0;n<4;++n)
        bf[n] = *(const bf16x8*)(Bs + swz128((brow + n*16)*128 + ks*64 + kbOff));
      #pragma unroll
      for (int m=0;m<4;++m)
        #pragma unroll
        for (int n=0;n<4;++n)
          acc[m][n] = mfma16(af[m], bf[n], acc[m][n]);
    }
    __syncthreads();
  }
  #pragma unroll
  for (int m=0;m<4;++m) {
    #pragma unroll
    for (int n=0;n<4;++n) {
      #pragma unroll
      for (int i=0;i<4;++i) {
        int row = m0 + wr*64 + m*16 + (lane>>4)*4 + i;
        int col = n0 + wc*64 + n*16 + (lane&15);
        float v = acc[m][n][i];
        if (EPI==2) {
          Cf[(size_t)row*N + col] = v + bias[col];   // fp32 final output
        } else {
          C[(size_t)row*N + col] = __float2bfloat16(v);
          if (EPI==1 && col >= 384) {   // v-half: also write transposed per head
            int bb = row / 784;
            int p  = row - bb*784;
            int cc = col - 384;
            int hh = cc >> 6, dd = cc & 63;
            vT[(size_t)((bb*6+hh)*64+dd)*784 + p] = __float2bfloat16(v);
          }
        }
      }
    }
  }
}

// ---------------- flash attention v3: fixed-offset softmax, swapped QK -------
// 64 q-rows/block, KVBLK=64, K/V double-buffered, LDS 40960 -> 4 blocks/CU.
// mfma(K,Q) gives S^T: lane holds kv=(lane>>4)*4+i+16nf (4 contiguous), q=lane&15
// -> P written as 4x ds_write_b64, no shuffles in the loop, no online max.
__global__ __launch_bounds__(256,4) void attn_kernel(
    const __hip_bfloat16* __restrict__ qb, const __hip_bfloat16* __restrict__ kvb,
    const __hip_bfloat16* __restrict__ vTb, __hip_bfloat16* __restrict__ ob)
{
  __shared__ __align__(1024) char Ks[2*8192];   // [buf][64 kv x 64 d] swz128
  __shared__ __align__(1024) char Vs[2*8192];   // [buf][64 d x 64 kv] swz128
  __shared__ __align__(1024) char Ps[4*2048];   // per-wave [16 q x 64 kv] swz128
  const int t = threadIdx.x, lane = t&63, w = t>>6;
  const int bh = blockIdx.y;
  const int b = bh / 6, h = bh - b*6;
  const int qp0 = blockIdx.x * 64;

  // exp2-domain: P = 2^(S*0.125*log2e - C2); offset cancels in normalization
  const float K1 = 0.18033688011112042f;   // 0.125 * log2(e)
  const float C2 = 5.770780163555851f;     // 4.0  * log2(e)

  // Q fragments direct from global (used as MFMA B-operand; same lane map)
  const char* qrow = (const char*)qb
      + ((size_t)(b*3136 + qp0 + w*16 + (lane&15))*384 + h*64)*2 + (lane>>4)*16;
  bf16x8 aq[2];
  aq[0] = *(const bf16x8*)(qrow);
  aq[1] = *(const bf16x8*)(qrow + 64);

  const char* kbase = (const char*)kvb + ((size_t)(b*784)*768 + h*64)*2;  // row 1536B
  const char* vbase = (const char*)vTb + (size_t)((b*6+h)*64)*1568;       // row 1568B

  const uint32_t d0 = (uint32_t)t*16u, d1 = (uint32_t)(256+t)*16u;
  const uint32_t l0 = swz128(d0), l1 = swz128(d1);
  const int      kr0 = (int)(l0>>7), kr1 = (int)(l1>>7);
  const uint32_t c0 = l0&127u, c1 = l1&127u;

  #define STAGE(buf, kv0) do {                                               \
    int a0 = (kv0)+kr0; if (a0>783) a0=783;                                  \
    int a1 = (kv0)+kr1; if (a1>783) a1=783;                                  \
    gl_lds16(kbase + (size_t)a0*1536 + c0, Ks + (buf)*8192 + d0);            \
    gl_lds16(kbase + (size_t)a1*1536 + c1, Ks + (buf)*8192 + d1);            \
    gl_lds16(vbase + (size_t)kr0*1568 + (size_t)(kv0)*2 + c0, Vs + (buf)*8192 + d0); \
    gl_lds16(vbase + (size_t)kr1*1568 + (size_t)(kv0)*2 + c1, Vs + (buf)*8192 + d1); \
  } while(0)

  STAGE(0, 0);
  asm volatile("s_waitcnt vmcnt(0)" ::: "memory");
  __syncthreads();

  float l_part = 0.f;
  f32x4 o[4];
  #pragma unroll
  for (int nf=0;nf<4;++nf) o[nf] = f32x4{0.f,0.f,0.f,0.f};

  char* Pb = Ps + w*2048;
  const uint32_t fragOff = (uint32_t)((lane>>4)*16);
  // P write base: q=lane&15 row, kv 4-contig block at (lane>>4)*4 (+16 per frag)
  const uint32_t pwBase = (uint32_t)(lane&15)*128 + (uint32_t)((lane>>4)*4)*2;

  for (int kt=0; kt<13; ++kt) {
    const int cur = kt & 1;
    STAGE(cur^1, (kt+1)*64);          // prefetch next tile (whole iter to land)
    const char* Kb = Ks + cur*8192;
    const char* Vb = Vs + cur*8192;

    // S^T = (K Q^T): s[nf][i] = S[kv=nf*16+(lane>>4)*4+i][q=lane&15]
    f32x4 s[4];
    #pragma unroll
    for (int nf=0;nf<4;++nf) s[nf] = f32x4{0.f,0.f,0.f,0.f};
    #pragma unroll
    for (int nf=0;nf<4;++nf) {
      #pragma unroll
      for (int ks=0;ks<2;++ks) {
        bf16x8 kf = *(const bf16x8*)(Kb + swz128((uint32_t)(nf*16+(lane&15))*128 + ks*64 + fragOff));
        s[nf] = mfma16(kf, aq[ks], s[nf]);
      }
    }

    // P = 2^(S*K1 - C2); tail tile: only frag nf=0 is valid (kv 768..783)
    #pragma unroll
    for (int nf=0;nf<4;++nf) {
      uint64_t pk;
      if (kt == 12 && nf > 0) {
        pk = 0ull;
      } else {
        float p0 = exp2f(fmaf(s[nf][0], K1, -C2));
        float p1 = exp2f(fmaf(s[nf][1], K1, -C2));
        float p2 = exp2f(fmaf(s[nf][2], K1, -C2));
        float p3 = exp2f(fmaf(s[nf][3], K1, -C2));
        l_part += (p0+p1) + (p2+p3);
        pk = (uint64_t)pkbf(p2,p3) << 32 | pkbf(p0,p1);
      }
      *(uint64_t*)(Pb + swz128(pwBase + nf*32)) = pk;
    }

    // O += P V
    #pragma unroll
    for (int ks=0;ks<2;++ks) {
      bf16x8 pa = *(const bf16x8*)(Pb + swz128((uint32_t)(lane&15)*128 + ks*64 + fragOff));
      #pragma unroll
      for (int nf=0;nf<4;++nf) {
        bf16x8 vf = *(const bf16x8*)(Vb + swz128((uint32_t)(nf*16+(lane&15))*128 + ks*64 + fragOff));
        o[nf] = mfma16(pa, vf, o[nf]);
      }
    }

    asm volatile("s_waitcnt vmcnt(0)" ::: "memory");  // next tile staged
    __syncthreads();                                   // + all waves done w/ cur
  }
  #undef STAGE

  // l reduce: groups (lane>>4) hold disjoint kv subsets for q=lane&15
  l_part += __shfl_xor(l_part, 16);
  l_part += __shfl_xor(l_part, 32);

  char* obase = (char*)ob + ((size_t)(b*3136 + qp0 + w*16 + (lane>>4)*4)*384 + h*64 + (lane&15))*2;
  #pragma unroll
  for (int i=0;i<4;++i) {
    float li = __shfl(l_part, (lane>>4)*4 + i);   // l for q-row (lane>>4)*4+i
    float inv = 1.0f / li;
    #pragma unroll
    for (int nf=0;nf<4;++nf)
      *(__hip_bfloat16*)(obase + (size_t)i*768 + nf*32) = __float2bfloat16(o[nf][i]*inv);
  }
}

// ---------------- launch --------------------------------------------------
extern "C" void kernel_launch(void* const* d_in, const int* in_sizes, int n_in,
                              void* d_out, int out_size, void* d_ws, size_t ws_size,
                              hipStream_t stream)
{
  const float* x      = (const float*)d_in[0];
  const float* wdwq   = (const float*)d_in[1];
  const float* gq     = (const float*)d_in[2];
  const float* bq     = (const float*)d_in[3];
  const float* mq     = (const float*)d_in[4];
  const float* vq     = (const float*)d_in[5];
  const float* wpwq   = (const float*)d_in[6];
  const float* wdwkv  = (const float*)d_in[7];
  const float* gkv    = (const float*)d_in[8];
  const float* bkv    = (const float*)d_in[9];
  const float* mkv    = (const float*)d_in[10];
  const float* vkv    = (const float*)d_in[11];
  const float* wpwkv  = (const float*)d_in[12];
  const float* wout   = (const float*)d_in[13];
  const float* bout   = (const float*)d_in[14];

  char* ws = (char*)d_ws;
  __hip_bfloat16* yq    = (__hip_bfloat16*)(ws + 0);          // 25088x384 (reused as o)
  __hip_bfloat16* qbuf  = (__hip_bfloat16*)(ws + 19267584);   // 25088x384
  __hip_bfloat16* ykv   = (__hip_bfloat16*)(ws + 38535168);   // 6272x384
  __hip_bfloat16* kvbuf = (__hip_bfloat16*)(ws + 43352064);   // 6272x768
  __hip_bfloat16* vT    = (__hip_bfloat16*)(ws + 52985856);   // 48x64x784 (+64K slack)
  __hip_bfloat16* wTq   = (__hip_bfloat16*)(ws + 57868288);   // 384x384
  __hip_bfloat16* wTkv  = (__hip_bfloat16*)(ws + 58163200);   // 768x384
  __hip_bfloat16* wTo   = (__hip_bfloat16*)(ws + 58753024);   // 384x384

  dwconv_bn_kernel<<<dim3(37632),256,0,stream>>>(x,wdwq,gq,bq,mq,vq,yq,56,1,1,9633792);
  dwconv_bn_kernel<<<dim3(9408),256,0,stream>>>(x,wdwkv,gkv,bkv,mkv,vkv,ykv,28,2,0,2408448);
  transpose_all_kernel<<<dim3(2304),256,0,stream>>>(wpwq, wpwkv, wout, wTq, wTkv, wTo);
  gemm128_kernel<0><<<dim3(3,196),256,0,stream>>>(yq, wTq, qbuf, nullptr, 25088,384,384, nullptr, nullptr);
  gemm128_kernel<1><<<dim3(6,49),256,0,stream>>>(ykv, wTkv, kvbuf, nullptr, 6272,768,384, nullptr, vT);
  attn_kernel<<<dim3(49,48),256,0,stream>>>(qbuf, kvbuf, vT, yq);
  gemm128_kernel<2><<<dim3(3,196),256,0,stream>>>(yq, wTo, nullptr, (float*)d_out, 25088,384,384, bout, nullptr);
}

// Round 9
// 276.129 us; speedup vs baseline: 1.3734x; 1.2086x over previous
//
#include <hip/hip_runtime.h>
#include <hip/hip_bf16.h>
#include <stdint.h>

typedef float  f32x4  __attribute__((ext_vector_type(4)));
typedef __bf16 bf16x8 __attribute__((ext_vector_type(8)));

#define DEV static __device__ __forceinline__

// XOR swizzle for LDS tiles with 128B rows: byte ^= ((row&7)<<4), row = byte>>7
DEV uint32_t swz128(uint32_t b){ return b ^ ((b>>3)&0x70u); }

// async global->LDS, 16B per lane; LDS dest = wave-uniform base + lane*16
DEV void gl_lds16(const void* g, void* l) {
  __builtin_amdgcn_global_load_lds(
      (__attribute__((address_space(1))) void*)(g),
      (__attribute__((address_space(3))) void*)(l), 16, 0, 0);
}

DEV f32x4 mfma16(bf16x8 a, bf16x8 b, f32x4 c) {
  return __builtin_amdgcn_mfma_f32_16x16x32_bf16(a, b, c, 0, 0, 0);
}

DEV uint32_t pkbf(float a, float b) {
  union { __hip_bfloat162 v; uint32_t u; } c;
  c.v.x = __float2bfloat16(a);
  c.v.y = __float2bfloat16(b);
  return c.u;
}

// ------- depthwise 3x3 conv + BN, float4-vectorized, XCD-chunked -------------
// thread = (b, i, j, c4) with c4 = 4-channel group (96/row). One batch image
// per XCD chunk -> row re-reads hit that XCD's L2 instead of HBM.
template<int HOUT, int STRIDE, int PAD>
__global__ __launch_bounds__(256) void dwconv_bn_v4(
    const float* __restrict__ x, const float* __restrict__ wdw,
    const float* __restrict__ gamma, const float* __restrict__ beta,
    const float* __restrict__ mean, const float* __restrict__ var,
    __hip_bfloat16* __restrict__ y)
{
  constexpr int TOTAL4 = 8*HOUT*HOUT*96;
  constexpr int NWG = (TOTAL4 + 255)/256;
  const int wg = blockIdx.x;
  const int xcd = wg & 7, o = wg >> 3;
  constexpr int qq = NWG >> 3, rr = NWG & 7;
  const int swz = (xcd < rr ? xcd*(qq+1) : rr*(qq+1) + (xcd-rr)*qq) + o;
  const int idx = swz*256 + (int)threadIdx.x;
  if (idx >= TOTAL4) return;
  const int c4 = idx % 96;
  int t = idx / 96;
  const int j = t % HOUT; t /= HOUT;
  const int i = t % HOUT; const int b = t / HOUT;

  const float* xb = x + (size_t)b*(56*56*384) + c4*4;
  f32x4 acc = {0.f,0.f,0.f,0.f};
  #pragma unroll
  for (int di=0; di<3; ++di) {
    const int ii = i*STRIDE + di - PAD;
    if ((unsigned)ii < 56u) {
      #pragma unroll
      for (int dj=0; dj<3; ++dj) {
        const int jj = j*STRIDE + dj - PAD;
        if ((unsigned)jj < 56u) {
          f32x4 xv = *(const f32x4*)(xb + ((size_t)ii*56 + jj)*384);
          f32x4 wv = *(const f32x4*)(wdw + (di*3+dj)*384 + c4*4);
          acc += xv*wv;
        }
      }
    }
  }
  f32x4 g  = *(const f32x4*)(gamma + c4*4);
  f32x4 be = *(const f32x4*)(beta  + c4*4);
  f32x4 mu = *(const f32x4*)(mean  + c4*4);
  f32x4 va = *(const f32x4*)(var   + c4*4);
  union { ushort u[4]; uint2 v; } pk;
  #pragma unroll
  for (int k=0;k<4;++k) {
    float sc = g[k]*rsqrtf(va[k]+1e-5f);
    union { __hip_bfloat16 h; ushort s; } cv;
    cv.h = __float2bfloat16((acc[k]-mu[k])*sc + be[k]);
    pk.u[k] = cv.s;
  }
  *(uint2*)((char*)y + (size_t)idx*8) = pk.v;
}

// ---------------- merged weight transposes: w(K,N) fp32 -> wT(N,K) bf16 ------
__global__ __launch_bounds__(256) void transpose_all_kernel(
    const float* __restrict__ wq, const float* __restrict__ wkv,
    const float* __restrict__ wo,
    __hip_bfloat16* __restrict__ wTq, __hip_bfloat16* __restrict__ wTkv,
    __hip_bfloat16* __restrict__ wTo)
{
  int i = blockIdx.x*256 + threadIdx.x;
  if (i < 147456) {                       // 384x384
    int n = i / 384, k = i - n*384;
    wTq[i] = __float2bfloat16(wq[(size_t)k*384 + n]);
  } else if (i < 147456 + 294912) {       // 768x384 (N=768)
    int idx = i - 147456;
    int n = idx / 384, k = idx - n*384;
    wTkv[idx] = __float2bfloat16(wkv[(size_t)k*768 + n]);
  } else if (i < 147456 + 294912 + 147456) {
    int idx = i - 442368;
    int n = idx / 384, k = idx - n*384;
    wTo[idx] = __float2bfloat16(wo[(size_t)k*384 + n]);
  }
}

// ---------------- 128x128x(K) bf16 GEMM, Bt = B^T (N,K) row-major ------------
// EPI 0: C=bf16 store. EPI 1: + scatter v-half transposed to vT[bh][d][p].
// EPI 2: bias + FP32 store to Cf (final output buffer is float).
template<int EPI>
__global__ __launch_bounds__(256,2) void gemm128_kernel(
    const __hip_bfloat16* __restrict__ A, const __hip_bfloat16* __restrict__ Bt,
    __hip_bfloat16* __restrict__ C, float* __restrict__ Cf, int M, int N, int K,
    const float* __restrict__ bias, __hip_bfloat16* __restrict__ vT)
{
  __shared__ __align__(1024) char As[128*64*2];
  __shared__ __align__(1024) char Bs[128*64*2];
  const int t = threadIdx.x;
  const int lane = t & 63;
  const int wave = t >> 6;
  const int wr = wave >> 1, wc = wave & 1;
  const int m0 = blockIdx.y*128, n0 = blockIdx.x*128;
  const int ldab = K*2;

  const char* aS[4]; const char* bS[4];
  #pragma unroll
  for (int j=0;j<4;++j) {
    uint32_t d = (uint32_t)(j*256 + t)*16u;
    uint32_t l = swz128(d);
    uint32_t r = l >> 7, cb = l & 127u;
    aS[j] = (const char*)A  + (size_t)(m0+(int)r)*ldab + cb;
    bS[j] = (const char*)Bt + (size_t)(n0+(int)r)*ldab + cb;
  }
  f32x4 acc[4][4];
  #pragma unroll
  for (int m=0;m<4;++m)
    #pragma unroll
    for (int n=0;n<4;++n)
      acc[m][n] = f32x4{0.f,0.f,0.f,0.f};

  const uint32_t kbOff = (uint32_t)((lane>>4)*16);
  const uint32_t arow = (uint32_t)(wr*64 + (lane&15));
  const uint32_t brow = (uint32_t)(wc*64 + (lane&15));

  const int nk = K >> 6;
  for (int kt=0; kt<nk; ++kt) {
    #pragma unroll
    for (int j=0;j<4;++j) {
      uint32_t d = (uint32_t)(j*256+t)*16u;
      gl_lds16(aS[j] + (size_t)kt*128, As + d);
      gl_lds16(bS[j] + (size_t)kt*128, Bs + d);
    }
    __syncthreads();
    #pragma unroll
    for (int ks=0;ks<2;++ks) {
      bf16x8 af[4], bf[4];
      #pragma unroll
      for (int m=0;m<4;++m)
        af[m] = *(const bf16x8*)(As + swz128((arow + m*16)*128 + ks*64 + kbOff));
      #pragma unroll
      for (int n=0;n<4;++n)
        bf[n] = *(const bf16x8*)(Bs + swz128((brow + n*16)*128 + ks*64 + kbOff));
      #pragma unroll
      for (int m=0;m<4;++m)
        #pragma unroll
        for (int n=0;n<4;++n)
          acc[m][n] = mfma16(af[m], bf[n], acc[m][n]);
    }
    __syncthreads();
  }
  #pragma unroll
  for (int m=0;m<4;++m) {
    #pragma unroll
    for (int n=0;n<4;++n) {
      #pragma unroll
      for (int i=0;i<4;++i) {
        int row = m0 + wr*64 + m*16 + (lane>>4)*4 + i;
        int col = n0 + wc*64 + n*16 + (lane&15);
        float v = acc[m][n][i];
        if (EPI==2) {
          Cf[(size_t)row*N + col] = v + bias[col];   // fp32 final output
        } else {
          C[(size_t)row*N + col] = __float2bfloat16(v);
          if (EPI==1 && col >= 384) {   // v-half: also write transposed per head
            int bb = row / 784;
            int p  = row - bb*784;
            int cc = col - 384;
            int hh = cc >> 6, dd = cc & 63;
            vT[(size_t)((bb*6+hh)*64+dd)*784 + p] = __float2bfloat16(v);
          }
        }
      }
    }
  }
}

// ---------------- flash attention v3: fixed-offset softmax, swapped QK -------
// 64 q-rows/block, KVBLK=64, K/V double-buffered, LDS 40960 -> 4 blocks/CU.
// mfma(K,Q) gives S^T: lane holds kv=(lane>>4)*4+i+16nf (4 contiguous), q=lane&15
// -> P written as 4x ds_write_b64, no shuffles in the loop, no online max.
__global__ __launch_bounds__(256,4) void attn_kernel(
    const __hip_bfloat16* __restrict__ qb, const __hip_bfloat16* __restrict__ kvb,
    const __hip_bfloat16* __restrict__ vTb, __hip_bfloat16* __restrict__ ob)
{
  __shared__ __align__(1024) char Ks[2*8192];   // [buf][64 kv x 64 d] swz128
  __shared__ __align__(1024) char Vs[2*8192];   // [buf][64 d x 64 kv] swz128
  __shared__ __align__(1024) char Ps[4*2048];   // per-wave [16 q x 64 kv] swz128
  const int t = threadIdx.x, lane = t&63, w = t>>6;
  const int bh = blockIdx.y;
  const int b = bh / 6, h = bh - b*6;
  const int qp0 = blockIdx.x * 64;

  // exp2-domain: P = 2^(S*0.125*log2e - C2); offset cancels in normalization
  const float K1 = 0.18033688011112042f;   // 0.125 * log2(e)
  const float C2 = 5.770780163555851f;     // 4.0  * log2(e)

  // Q fragments direct from global (used as MFMA B-operand; same lane map)
  const char* qrow = (const char*)qb
      + ((size_t)(b*3136 + qp0 + w*16 + (lane&15))*384 + h*64)*2 + (lane>>4)*16;
  bf16x8 aq[2];
  aq[0] = *(const bf16x8*)(qrow);
  aq[1] = *(const bf16x8*)(qrow + 64);

  const char* kbase = (const char*)kvb + ((size_t)(b*784)*768 + h*64)*2;  // row 1536B
  const char* vbase = (const char*)vTb + (size_t)((b*6+h)*64)*1568;       // row 1568B

  const uint32_t d0 = (uint32_t)t*16u, d1 = (uint32_t)(256+t)*16u;
  const uint32_t l0 = swz128(d0), l1 = swz128(d1);
  const int      kr0 = (int)(l0>>7), kr1 = (int)(l1>>7);
  const uint32_t c0 = l0&127u, c1 = l1&127u;

  #define STAGE(buf, kv0) do {                                               \
    int a0 = (kv0)+kr0; if (a0>783) a0=783;                                  \
    int a1 = (kv0)+kr1; if (a1>783) a1=783;                                  \
    gl_lds16(kbase + (size_t)a0*1536 + c0, Ks + (buf)*8192 + d0);            \
    gl_lds16(kbase + (size_t)a1*1536 + c1, Ks + (buf)*8192 + d1);            \
    gl_lds16(vbase + (size_t)kr0*1568 + (size_t)(kv0)*2 + c0, Vs + (buf)*8192 + d0); \
    gl_lds16(vbase + (size_t)kr1*1568 + (size_t)(kv0)*2 + c1, Vs + (buf)*8192 + d1); \
  } while(0)

  STAGE(0, 0);
  asm volatile("s_waitcnt vmcnt(0)" ::: "memory");
  __syncthreads();

  float l_part = 0.f;
  f32x4 o[4];
  #pragma unroll
  for (int nf=0;nf<4;++nf) o[nf] = f32x4{0.f,0.f,0.f,0.f};

  char* Pb = Ps + w*2048;
  const uint32_t fragOff = (uint32_t)((lane>>4)*16);
  // P write base: q=lane&15 row, kv 4-contig block at (lane>>4)*4 (+16 per frag)
  const uint32_t pwBase = (uint32_t)(lane&15)*128 + (uint32_t)((lane>>4)*4)*2;

  for (int kt=0; kt<13; ++kt) {
    const int cur = kt & 1;
    STAGE(cur^1, (kt+1)*64);          // prefetch next tile (whole iter to land)
    const char* Kb = Ks + cur*8192;
    const char* Vb = Vs + cur*8192;

    // S^T = (K Q^T): s[nf][i] = S[kv=nf*16+(lane>>4)*4+i][q=lane&15]
    f32x4 s[4];
    #pragma unroll
    for (int nf=0;nf<4;++nf) s[nf] = f32x4{0.f,0.f,0.f,0.f};
    #pragma unroll
    for (int nf=0;nf<4;++nf) {
      #pragma unroll
      for (int ks=0;ks<2;++ks) {
        bf16x8 kf = *(const bf16x8*)(Kb + swz128((uint32_t)(nf*16+(lane&15))*128 + ks*64 + fragOff));
        s[nf] = mfma16(kf, aq[ks], s[nf]);
      }
    }

    // P = 2^(S*K1 - C2); tail tile: only frag nf=0 is valid (kv 768..783)
    #pragma unroll
    for (int nf=0;nf<4;++nf) {
      uint64_t pk;
      if (kt == 12 && nf > 0) {
        pk = 0ull;
      } else {
        float p0 = exp2f(fmaf(s[nf][0], K1, -C2));
        float p1 = exp2f(fmaf(s[nf][1], K1, -C2));
        float p2 = exp2f(fmaf(s[nf][2], K1, -C2));
        float p3 = exp2f(fmaf(s[nf][3], K1, -C2));
        l_part += (p0+p1) + (p2+p3);
        pk = (uint64_t)pkbf(p2,p3) << 32 | pkbf(p0,p1);
      }
      *(uint64_t*)(Pb + swz128(pwBase + nf*32)) = pk;
    }

    // O += P V
    #pragma unroll
    for (int ks=0;ks<2;++ks) {
      bf16x8 pa = *(const bf16x8*)(Pb + swz128((uint32_t)(lane&15)*128 + ks*64 + fragOff));
      #pragma unroll
      for (int nf=0;nf<4;++nf) {
        bf16x8 vf = *(const bf16x8*)(Vb + swz128((uint32_t)(nf*16+(lane&15))*128 + ks*64 + fragOff));
        o[nf] = mfma16(pa, vf, o[nf]);
      }
    }

    asm volatile("s_waitcnt vmcnt(0)" ::: "memory");  // next tile staged
    __syncthreads();                                   // + all waves done w/ cur
  }
  #undef STAGE

  // l reduce: groups (lane>>4) hold disjoint kv subsets for q=lane&15
  l_part += __shfl_xor(l_part, 16);
  l_part += __shfl_xor(l_part, 32);

  char* obase = (char*)ob + ((size_t)(b*3136 + qp0 + w*16 + (lane>>4)*4)*384 + h*64 + (lane&15))*2;
  #pragma unroll
  for (int i=0;i<4;++i) {
    float li = __shfl(l_part, (lane>>4)*4 + i);   // l for q-row (lane>>4)*4+i
    float inv = 1.0f / li;
    #pragma unroll
    for (int nf=0;nf<4;++nf)
      *(__hip_bfloat16*)(obase + (size_t)i*768 + nf*32) = __float2bfloat16(o[nf][i]*inv);
  }
}

// ---------------- launch --------------------------------------------------
extern "C" void kernel_launch(void* const* d_in, const int* in_sizes, int n_in,
                              void* d_out, int out_size, void* d_ws, size_t ws_size,
                              hipStream_t stream)
{
  const float* x      = (const float*)d_in[0];
  const float* wdwq   = (const float*)d_in[1];
  const float* gq     = (const float*)d_in[2];
  const float* bq     = (const float*)d_in[3];
  const float* mq     = (const float*)d_in[4];
  const float* vq     = (const float*)d_in[5];
  const float* wpwq   = (const float*)d_in[6];
  const float* wdwkv  = (const float*)d_in[7];
  const float* gkv    = (const float*)d_in[8];
  const float* bkv    = (const float*)d_in[9];
  const float* mkv    = (const float*)d_in[10];
  const float* vkv    = (const float*)d_in[11];
  const float* wpwkv  = (const float*)d_in[12];
  const float* wout   = (const float*)d_in[13];
  const float* bout   = (const float*)d_in[14];

  char* ws = (char*)d_ws;
  __hip_bfloat16* yq    = (__hip_bfloat16*)(ws + 0);          // 25088x384 (reused as o)
  __hip_bfloat16* qbuf  = (__hip_bfloat16*)(ws + 19267584);   // 25088x384
  __hip_bfloat16* ykv   = (__hip_bfloat16*)(ws + 38535168);   // 6272x384
  __hip_bfloat16* kvbuf = (__hip_bfloat16*)(ws + 43352064);   // 6272x768
  __hip_bfloat16* vT    = (__hip_bfloat16*)(ws + 52985856);   // 48x64x784 (+64K slack)
  __hip_bfloat16* wTq   = (__hip_bfloat16*)(ws + 57868288);   // 384x384
  __hip_bfloat16* wTkv  = (__hip_bfloat16*)(ws + 58163200);   // 768x384
  __hip_bfloat16* wTo   = (__hip_bfloat16*)(ws + 58753024);   // 384x384

  dwconv_bn_v4<56,1,1><<<dim3(9408),256,0,stream>>>(x,wdwq,gq,bq,mq,vq,yq);
  dwconv_bn_v4<28,2,0><<<dim3(2352),256,0,stream>>>(x,wdwkv,gkv,bkv,mkv,vkv,ykv);
  transpose_all_kernel<<<dim3(2304),256,0,stream>>>(wpwq, wpwkv, wout, wTq, wTkv, wTo);
  gemm128_kernel<0><<<dim3(3,196),256,0,stream>>>(yq, wTq, qbuf, nullptr, 25088,384,384, nullptr, nullptr);
  gemm128_kernel<1><<<dim3(6,49),256,0,stream>>>(ykv, wTkv, kvbuf, nullptr, 6272,768,384, nullptr, vT);
  attn_kernel<<<dim3(49,48),256,0,stream>>>(qbuf, kvbuf, vT, yq);
  gemm128_kernel<2><<<dim3(3,196),256,0,stream>>>(yq, wTo, nullptr, (float*)d_out, 25088,384,384, bout, nullptr);
}